// Round 10
// baseline (245.996 us; speedup 1.0000x reference)
//
#include <hip/hip_runtime.h>
#include <hip/hip_bf16.h>
#include <hip/hip_fp16.h>
#include <cstddef>
#include <cstdint>

// Problem constants
#define BB 2
#define HH 128
#define WW 128
#define CC 256
#define WSZ 8
#define KWIN 16
#define NHEADS 8
#define HD 32
#define C3 768
#define NPIX 32768            // B*H*W
#define NWIN 512              // B * 16 * 16

typedef short    bf16x8 __attribute__((ext_vector_type(8)));
typedef _Float16 half8  __attribute__((ext_vector_type(8)));
typedef float    f32x4  __attribute__((ext_vector_type(4)));

#define LOG2E 1.4426950408889634f

#if __has_builtin(__builtin_amdgcn_exp2f)
#define EXP2(x) __builtin_amdgcn_exp2f(x)
#else
#define EXP2(x) __expf((x) * 0.6931471805599453f)
#endif

__device__ inline void gload_lds16(const _Float16* g, _Float16* l) {
    __builtin_amdgcn_global_load_lds(
        (const __attribute__((address_space(1))) unsigned int*)g,
        (__attribute__((address_space(3))) unsigned int*)l, 16, 0, 0);
}

// ---------------------------------------------------------------------------
// CPB MLP: bias_tab[529][8] = sigmoid(relu(tab @ w1 + b1) @ w2) * 16
// ---------------------------------------------------------------------------
__global__ __launch_bounds__(64) void cpb_kernel(const float* __restrict__ w1,
                                                 const float* __restrict__ b1,
                                                 const float* __restrict__ w2,
                                                 float* __restrict__ btab) {
    const int e = blockIdx.x;          // 0..528
    const int i = e / 23, j = e % 23;
    const float inv_log8 = 1.0f / logf(8.0f);
    float c0 = (float)(i - 11) * (8.0f / 7.0f);
    float c1 = (float)(j - 11) * (8.0f / 7.0f);
    float f0 = copysignf(log1pf(fabsf(c0)) * inv_log8, c0);
    float f1 = copysignf(log1pf(fabsf(c1)) * inv_log8, c1);

    const int t = threadIdx.x;
    float acc[8] = {0.f,0.f,0.f,0.f,0.f,0.f,0.f,0.f};
    for (int kk = 0; kk < 8; kk++) {
        int k = kk * 64 + t;
        float hid = f0 * w1[k] + f1 * w1[512 + k] + b1[k];
        hid = fmaxf(hid, 0.f);
        #pragma unroll
        for (int h = 0; h < 8; h++) acc[h] += hid * w2[k * 8 + h];
    }
    #pragma unroll
    for (int h = 0; h < 8; h++) {
        #pragma unroll
        for (int off = 32; off >= 1; off >>= 1) acc[h] += __shfl_xor(acc[h], off);
    }
    if (t < 8) {
        float v = acc[t];
        btab[e * 8 + t] = 16.0f / (1.0f + expf(-v));
    }
}

// ---------------------------------------------------------------------------
// depthwise weights fp32 -> fp16 table (9*768 elems)
// ---------------------------------------------------------------------------
__global__ __launch_bounds__(256) void cvt_wdw(const float* __restrict__ src,
                                               _Float16* __restrict__ dst) {
    int i = blockIdx.x * 256 + threadIdx.x;
    if (i < 9 * C3) dst[i] = (_Float16)src[i];
}

// ---------------------------------------------------------------------------
// transpose + convert: src fp32 [R][Cn] -> dst fp16 [Cn][R].  32x32 LDS tile.
// ---------------------------------------------------------------------------
__global__ __launch_bounds__(256) void transpose_cvt(const float* __restrict__ src,
                                                     _Float16* __restrict__ dst,
                                                     int R, int Cn) {
    __shared__ float t[32][33];
    const int bx = blockIdx.x, by = blockIdx.y;
    const int tx = threadIdx.x & 31, ty = threadIdx.x >> 5;
    #pragma unroll
    for (int i = 0; i < 4; i++) {
        int r = by * 32 + ty + i * 8;
        t[ty + i * 8][tx] = src[(size_t)r * Cn + bx * 32 + tx];
    }
    __syncthreads();
    #pragma unroll
    for (int i = 0; i < 4; i++) {
        int dr = bx * 32 + ty + i * 8;          // orig col
        dst[(size_t)dr * R + by * 32 + tx] = (_Float16)t[tx][ty + i * 8];
    }
}

// ---------------------------------------------------------------------------
// fp16 MFMA NT-GEMM:  C[M][N] = A[M][K] * Bt[N][K]^T, fp32 accumulate.
// 128x128 tile, BK=64, 256 threads (4 waves, 2x2 of 64x64).
// LDS layout contract: physical k-slot p at row m holds logical group
// p ^ (m&7); fragment reads undo via phys = logical ^ (l15&7).
// ---------------------------------------------------------------------------
template <typename OT>
__global__ __launch_bounds__(256) void gemm_f16(const _Float16* __restrict__ A,
                                                const _Float16* __restrict__ Bt,
                                                OT* __restrict__ C,
                                                int M, int N, int K) {
    __shared__ _Float16 Ash[128][64];
    __shared__ _Float16 Bsh[128][64];
    const int tid = threadIdx.x;
    const int wv = tid >> 6, ln = tid & 63;
    const int quad = ln >> 4, l15 = ln & 15;
    const int rowb = blockIdx.y * 128;
    const int colb = blockIdx.x * 128;
    const int wm = (wv >> 1) * 64, wn = (wv & 1) * 64;

    const int r8 = ln >> 3, g = ln & 7;
    const int kg = g ^ r8;                    // swizzled logical k-group

    f32x4 acc[4][4] = {};
    for (int k0 = 0; k0 < K; k0 += 64) {
        #pragma unroll
        for (int i = 0; i < 4; i++) {
            const int m = wv * 32 + i * 8 + r8;
            gload_lds16(A + (size_t)(rowb + m) * K + k0 + kg * 8,
                        &Ash[wv * 32 + i * 8][0]);
            gload_lds16(Bt + (size_t)(colb + m) * K + k0 + kg * 8,
                        &Bsh[wv * 32 + i * 8][0]);
        }
        __syncthreads();
        #pragma unroll
        for (int kk = 0; kk < 2; kk++) {
            const int phys = ((kk * 4 + quad) ^ (l15 & 7)) * 8;
            half8 a[4], b[4];
            #pragma unroll
            for (int i = 0; i < 4; i++)
                a[i] = *(const half8*)&Ash[wm + i * 16 + l15][phys];
            #pragma unroll
            for (int j = 0; j < 4; j++)
                b[j] = *(const half8*)&Bsh[wn + j * 16 + l15][phys];
            #pragma unroll
            for (int i = 0; i < 4; i++)
                #pragma unroll
                for (int j = 0; j < 4; j++)
                    acc[i][j] = __builtin_amdgcn_mfma_f32_16x16x32_f16(
                        a[i], b[j], acc[i][j], 0, 0, 0);
        }
        __syncthreads();
    }
    #pragma unroll
    for (int i = 0; i < 4; i++) {
        #pragma unroll
        for (int reg = 0; reg < 4; reg++) {
            const size_t row = rowb + wm + i * 16 + quad * 4 + reg;
            #pragma unroll
            for (int j = 0; j < 4; j++) {
                C[row * N + colb + wn + j * 16 + l15] = (OT)acc[i][j][reg];
            }
        }
    }
}

// ---------------------------------------------------------------------------
// qkv GEMM with fused fp32->fp16 A conversion (A = x fp32 [M][K]).
// Manual A staging must honor the layout contract (phys p holds logical
// p^(m&7)): lane loads logical group g and writes phys slot g^r8 — correct
// AND conflict-free (fixed g, varying r8 sweeps all 8 bank windows).
// ---------------------------------------------------------------------------
__global__ __launch_bounds__(256) void gemm_qkv(const float* __restrict__ A,
                                                const _Float16* __restrict__ Bt,
                                                _Float16* __restrict__ C,
                                                int M, int N, int K) {
    __shared__ _Float16 Ash[128][64];
    __shared__ _Float16 Bsh[128][64];
    const int tid = threadIdx.x;
    const int wv = tid >> 6, ln = tid & 63;
    const int quad = ln >> 4, l15 = ln & 15;
    const int rowb = blockIdx.y * 128;
    const int colb = blockIdx.x * 128;
    const int wm = (wv >> 1) * 64, wn = (wv & 1) * 64;
    const int r8 = ln >> 3, g = ln & 7;
    const int kg = g ^ r8;

    f32x4 acc[4][4] = {};
    for (int k0 = 0; k0 < K; k0 += 64) {
        #pragma unroll
        for (int i = 0; i < 4; i++) {
            const int m = wv * 32 + i * 8 + r8;
            // load LOGICAL group g, write PHYSICAL slot g^r8
            const float* ap = A + (size_t)(rowb + m) * K + k0 + g * 8;
            const float4 a0 = *(const float4*)ap;
            const float4 a1 = *(const float4*)(ap + 4);
            half8 hv;
            hv[0] = (_Float16)a0.x; hv[1] = (_Float16)a0.y;
            hv[2] = (_Float16)a0.z; hv[3] = (_Float16)a0.w;
            hv[4] = (_Float16)a1.x; hv[5] = (_Float16)a1.y;
            hv[6] = (_Float16)a1.z; hv[7] = (_Float16)a1.w;
            *(half8*)&Ash[wv * 32 + i * 8 + r8][kg * 8] = hv;
            gload_lds16(Bt + (size_t)(colb + m) * K + k0 + kg * 8,
                        &Bsh[wv * 32 + i * 8][0]);
        }
        __syncthreads();
        #pragma unroll
        for (int kk = 0; kk < 2; kk++) {
            const int phys = ((kk * 4 + quad) ^ (l15 & 7)) * 8;
            half8 a[4], b[4];
            #pragma unroll
            for (int i = 0; i < 4; i++)
                a[i] = *(const half8*)&Ash[wm + i * 16 + l15][phys];
            #pragma unroll
            for (int j = 0; j < 4; j++)
                b[j] = *(const half8*)&Bsh[wn + j * 16 + l15][phys];
            #pragma unroll
            for (int i = 0; i < 4; i++)
                #pragma unroll
                for (int j = 0; j < 4; j++)
                    acc[i][j] = __builtin_amdgcn_mfma_f32_16x16x32_f16(
                        a[i], b[j], acc[i][j], 0, 0, 0);
        }
        __syncthreads();
    }
    #pragma unroll
    for (int i = 0; i < 4; i++) {
        #pragma unroll
        for (int reg = 0; reg < 4; reg++) {
            const size_t row = rowb + wm + i * 16 + quad * 4 + reg;
            #pragma unroll
            for (int j = 0; j < 4; j++) {
                C[row * N + colb + wn + j * 16 + l15] = (_Float16)acc[i][j][reg];
            }
        }
    }
}

// ---------------------------------------------------------------------------
// Depthwise 3x3 conv (SAME) + LayerNorm(768) + qkv bias + Q/K PRE-NORMALIZE.
// v11: 2D 8x2 PIXEL TILE (was 1x8 strip).  Halo cells 10x4 = 40 for 16
// pixels -> staging amplification 2.5x (strip: 30/8 = 3.75x) — 33% fewer
// staged bytes and 37% less per-pixel staging VALU.  Per-third staging:
// 40 cells x 32 units = 1280 half8 units = 20KB, double-buffered 40KB =
// exactly 160KB/4 blocks per CU (sred ALIASED into S[0] after conv).
// Thread map: wave w, lane l: pixel (py=w&1, px=l&7), group-slot
// gs=(l>>3)+8*(w>>1); thread handles groups gs and gs+16 per third.
// LN: local sum -> shfl_xor 8/16/32 (wave-half partial over 16 groups x3)
// -> sred[2][16] combine.  Q/K head-norm: shfl_xor 8/16 only (the head's
// 4 groups form a quad closed under gs-bit0/bit1 flips; xor32 would mix
// head sets — omitted).  Conv reads keep XOR swizzle
// phys=(u&~7)|((u^cc)&7): consecutive 8 lanes have px 0..7 -> 8 distinct
// bank windows -> conflict-free.  Q scaled by lscale*log2e per head.
// ---------------------------------------------------------------------------
__global__ __launch_bounds__(256) void dwconv_ln(const _Float16* __restrict__ in,
                                                 const _Float16* __restrict__ wdwh,
                                                 const float* __restrict__ g,
                                                 const float* __restrict__ bt,
                                                 const float* __restrict__ qb,
                                                 const float* __restrict__ vb,
                                                 const float* __restrict__ logit_scale,
                                                 _Float16* __restrict__ out) {
    __shared__ __align__(16) _Float16 S[2][1280 * 8];   // 40960 B total
    float* sred = (float*)&S[0][0];      // aliased AFTER conv: [2][16][2]

    const int t = threadIdx.x;
    const int bid = blockIdx.x;                  // NPIX/16 = 2048
    const int b   = bid >> 10;
    const int rem = bid & 1023;
    const int ty  = rem >> 4;                    // 0..63
    const int tx  = rem & 15;                    // 0..15
    const int y0  = ty * 2, x0 = tx * 8;

    const int w = t >> 6, l = t & 63;
    const int py = w & 1, px = l & 7;
    const int p  = py * 8 + px;                  // 0..15
    const int gs = (l >> 3) + ((w >> 1) << 3);   // 0..15

    const float lsc0 = __expf(fminf(logit_scale[gs >> 2], 4.60517019f)) * LOG2E;
    const float lsc1 = __expf(fminf(logit_scale[(gs >> 2) + 4], 4.60517019f)) * LOG2E;

    // ---- phase-invariant staging descriptors: 5 units/thread = 1280 ----
    const _Float16* sp[5];
    int sphys[5];
    bool sok[5];
    #pragma unroll
    for (int k = 0; k < 5; k++) {
        const int u = t + k * 256;
        const int cell = u >> 5, grp = u & 31;
        const int rr = cell / 10, cc = cell - rr * 10;
        const int yy = y0 + rr - 1, xx = x0 + cc - 1;
        const bool inb = ((unsigned)yy < 128u) && ((unsigned)xx < 128u);
        sok[k] = inb;
        sp[k] = in + (((size_t)(b * 128 + (inb ? yy : 0)) * 128 + (inb ? xx : 0)) * C3)
                   + grp * 8;
        sphys[k] = (u & ~7) | ((u ^ cc) & 7);
    }

    auto STAGE = [&](int s, int buf) {
        #pragma unroll
        for (int k = 0; k < 5; k++) {
            half8 v = (half8)(_Float16)0;
            if (sok[k]) v = *(const half8*)(sp[k] + s * 256);
            *(half8*)&S[buf][sphys[k] * 8] = v;
        }
    };

    STAGE(0, 0);
    float acc[3][2][8] = {};
    #pragma unroll
    for (int s = 0; s < 3; s++) {
        __syncthreads();
        if (s < 2) STAGE(s + 1, (s + 1) & 1);    // prefetch next third
        const _Float16* Sb = &S[s & 1][0];
        #pragma unroll
        for (int m = 0; m < 2; m++) {
            const int grp = gs + m * 16;
            half8 wv[9];
            #pragma unroll
            for (int tap = 0; tap < 9; tap++)
                wv[tap] = *(const half8*)(wdwh + (tap * 96 + s * 32 + grp) * 8);
            #pragma unroll
            for (int dy = 0; dy < 3; dy++) {
                #pragma unroll
                for (int dx = 0; dx < 3; dx++) {
                    const int cc = px + dx;
                    const int u = ((py + dy) * 10 + cc) * 32 + grp;
                    const int phys = (u & ~7) | ((u ^ cc) & 7);
                    const half8 v = *(const half8*)&Sb[phys * 8];
                    const half8 wt = wv[dy * 3 + dx];
                    #pragma unroll
                    for (int i = 0; i < 8; i++)
                        acc[s][m][i] += (float)v[i] * (float)wt[i];
                }
            }
        }
    }

    // ---- LayerNorm reduction over 768 ch of pixel p ----
    float ls = 0.f, lss = 0.f;
    #pragma unroll
    for (int s = 0; s < 3; s++)
        #pragma unroll
        for (int m = 0; m < 2; m++)
            #pragma unroll
            for (int i = 0; i < 8; i++) { ls += acc[s][m][i]; lss += acc[s][m][i] * acc[s][m][i]; }
    ls  += __shfl_xor(ls, 8);  lss += __shfl_xor(lss, 8);
    ls  += __shfl_xor(ls, 16); lss += __shfl_xor(lss, 16);
    ls  += __shfl_xor(ls, 32); lss += __shfl_xor(lss, 32);
    __syncthreads();                     // all conv reads of S done before aliasing
    if (l < 8) {
        sred[(((w >> 1) << 4) + (py << 3) + l) * 2 + 0] = ls;
        sred[(((w >> 1) << 4) + (py << 3) + l) * 2 + 1] = lss;
    }
    __syncthreads();
    const float Ssum  = sred[p * 2 + 0] + sred[(16 + p) * 2 + 0];
    const float SSsum = sred[p * 2 + 1] + sred[(16 + p) * 2 + 1];
    const float mu  = Ssum * (1.0f / 768.0f);
    const float var = SSsum * (1.0f / 768.0f) - mu * mu;
    const float rs  = rsqrtf(var + 1e-5f);

    // ---- scale/shift + q/v bias + q/k head-normalize, store fp16 ----
    const size_t obase = (size_t)((b * 128 + y0 + py) * 128 + x0 + px) * C3;
    #pragma unroll
    for (int s = 0; s < 3; s++) {
        #pragma unroll
        for (int m = 0; m < 2; m++) {
            const int ch = (gs + m * 16) * 8 + s * 256;
            const float4 g0 = *(const float4*)(g + ch);
            const float4 g1 = *(const float4*)(g + ch + 4);
            const float4 b0 = *(const float4*)(bt + ch);
            const float4 b1 = *(const float4*)(bt + ch + 4);
            float gg[8] = {g0.x, g0.y, g0.z, g0.w, g1.x, g1.y, g1.z, g1.w};
            float bb[8] = {b0.x, b0.y, b0.z, b0.w, b1.x, b1.y, b1.z, b1.w};
            if (s == 0) {
                const float4 e0 = *(const float4*)(qb + ch);
                const float4 e1 = *(const float4*)(qb + ch + 4);
                bb[0] += e0.x; bb[1] += e0.y; bb[2] += e0.z; bb[3] += e0.w;
                bb[4] += e1.x; bb[5] += e1.y; bb[6] += e1.z; bb[7] += e1.w;
            } else if (s == 2) {
                const float4 e0 = *(const float4*)(vb + ch - 512);
                const float4 e1 = *(const float4*)(vb + ch - 512 + 4);
                bb[0] += e0.x; bb[1] += e0.y; bb[2] += e0.z; bb[3] += e0.w;
                bb[4] += e1.x; bb[5] += e1.y; bb[6] += e1.z; bb[7] += e1.w;
            }
            float of[8];
            #pragma unroll
            for (int i = 0; i < 8; i++)
                of[i] = (acc[s][m][i] - mu) * rs * gg[i] + bb[i];
            if (s < 2) {                 // q/k: l2-normalize per head (quad of gs)
                float s2 = 0.f;
                #pragma unroll
                for (int i = 0; i < 8; i++) s2 += of[i] * of[i];
                s2 += __shfl_xor(s2, 8);
                s2 += __shfl_xor(s2, 16);
                float scl = rsqrtf(fmaxf(s2, 1.55e-5f));
                if (s == 0) scl *= (m ? lsc1 : lsc0);
                #pragma unroll
                for (int i = 0; i < 8; i++) of[i] *= scl;
            }
            half8 o;
            #pragma unroll
            for (int i = 0; i < 8; i++) o[i] = (_Float16)of[i];
            *(half8*)(out + obase + ch) = o;
        }
    }
}

// ---------------------------------------------------------------------------
// MFMA halo window attention v7: swapped QK^T, lane-local P, bias-as-C-init,
// pre-normalized Q/K, and V back in the proven Vt[32][264] layout.
//
// R9 post-mortem: the Vt2 key-major swizzle RAISED bank conflicts
// (3.67M -> 4.72M) — the per-element scatter writes (32 XOR+add + b16
// stores) cost more than the reads saved; the old channel-major reads
// were already conflict-free under the 8-lane-phase model (row stride
// 528B = 33 words, odd multiple of 4).  v7 reverts to v4.1's Vt: simple
// b16 writes (2 lanes/bank = free), aligned b128 reads.
//
// P2SHIFT (+14 log2): static shift M=lscale+16 is the WORST-CASE logit
// bound; real max logits sit ~12 nats below, so unshifted p would be f16
// SUBNORMAL.  +14 lifts p into f16 normal range; p <= 2^14.2 < 65504,
// and the factor cancels exactly in d*inv.
// ---------------------------------------------------------------------------
#define P2SHIFT 14.0f

__global__ __launch_bounds__(256) void attn_mfma(const _Float16* __restrict__ qkv,
                                                 const float* __restrict__ bias_tab,
                                                 const float* __restrict__ logit_scale,
                                                 _Float16* __restrict__ out) {
    const int blk = blockIdx.x;
    const int h = blk & 7;
    const int wid = blk >> 3;
    const int b = wid >> 8;
    const int wy = (wid >> 4) & 15;
    const int wx = wid & 15;
    const int tid = threadIdx.x;
    const int wave = tid >> 6, lane = tid & 63;
    const int quad = lane >> 4, l15 = lane & 15;

    __shared__ __align__(16) _Float16 Bf[16 * 64 * 8];   // K in A-frag layout, 16 KB
    __shared__ __align__(16) _Float16 Vt[32][264];       // V^T f16, 16.5 KB
    __shared__ float btab[529];                          // (rb - M)*log2e + P2SHIFT

    const float lscale = __expf(fminf(logit_scale[h], 4.60517019f)); // ln(100)
    const float MshiftL2 = (lscale + 16.0f) * LOG2E - P2SHIFT;
    for (int e = tid; e < 529; e += 256)
        btab[e] = bias_tab[e * 8 + h] * LOG2E - MshiftL2;

    // ---- stage K (pure copy -> A-frag layout) and V^T, 1 key/thread ----
    {
        const int j = tid;                         // key 0..255
        const int kr = j >> 4, kcc = j & 15;
        const int gy = wy * 8 - 4 + kr, gx = wx * 8 - 4 + kcc;
        const bool inb = ((unsigned)gy < 128u) && ((unsigned)gx < 128u);
        const _Float16* p = qkv +
            (((size_t)(b * 128 + (inb ? gy : 0)) * 128 + (inb ? gx : 0)) * C3) +
            256 + h * HD;
        // K layout: tile nt, position pos
        const int nt  = ((j >> 5) << 1) | ((j >> 2) & 1);
        const int pos = (((j >> 3) & 3) << 2) | (j & 3);
        #pragma unroll
        for (int d8 = 0; d8 < 4; d8++) {
            half8 kk, vv;
            if (inb) { kk = *(const half8*)(p + d8 * 8); vv = *(const half8*)(p + 256 + d8 * 8); }
            else     { kk = (half8)(_Float16)0;          vv = (half8)(_Float16)0; }
            *(half8*)&Bf[((nt * 64) + d8 * 16 + pos) * 8] = kk;
            #pragma unroll
            for (int u = 0; u < 8; u++)
                Vt[d8 * 8 + u][j] = vv[u];
        }
    }

    // ---- per-wave Q B-fragment: direct load (pre-normalized & pre-scaled) ----
    const int qrow = wave * 16 + l15;
    const int qr = qrow >> 3, qc = qrow & 7;
    const int qy = wy * 8 + qr, qx = wx * 8 + qc;
    const half8 qfrag = *(const half8*)(qkv +
        (((size_t)(b * 128 + qy) * 128 + qx) * C3) + h * HD + quad * 8);
    __syncthreads();

    // ---- 8 chunks of 32 keys: bias-init -> S^T mfma -> exp2 -> PV ----
    // btab index for (ch,jj,reg): (qr - kr + 15)*23 + (qc - kc + 15)
    //   kr = 2ch + (quad>>1),  kc = (quad&1)*8 + 4jj + reg
    const int colbase = qc + 15 - ((quad & 1) << 3);
    const int rowq    = qr + 15 - (quad >> 1);
    float lsum = 0.f;
    f32x4 d0 = {0.f, 0.f, 0.f, 0.f};
    f32x4 d1 = {0.f, 0.f, 0.f, 0.f};
    #pragma unroll
    for (int ch = 0; ch < 8; ch++) {
        const half8 ka0 = *(const half8*)&Bf[((2 * ch)     * 64 + lane) * 8];
        const half8 ka1 = *(const half8*)&Bf[((2 * ch + 1) * 64 + lane) * 8];
        const float* bt = &btab[(rowq - 2 * ch) * 23 + colbase];
        f32x4 s0 = {bt[0],  bt[-1], bt[-2], bt[-3]};   // bias as C-init
        f32x4 s1 = {bt[-4], bt[-5], bt[-6], bt[-7]};
        __builtin_amdgcn_s_setprio(1);
        s0 = __builtin_amdgcn_mfma_f32_16x16x32_f16(ka0, qfrag, s0, 0, 0, 0);
        s1 = __builtin_amdgcn_mfma_f32_16x16x32_f16(ka1, qfrag, s1, 0, 0, 0);
        __builtin_amdgcn_s_setprio(0);
        half8 pa;
        #pragma unroll
        for (int r = 0; r < 4; r++) {
            const float p0 = EXP2(s0[r]);
            const float p1 = EXP2(s1[r]);
            lsum += p0 + p1;
            pa[r]     = (_Float16)p0;
            pa[4 + r] = (_Float16)p1;
        }
        const half8 v0 = *(const half8*)&Vt[l15][ch * 32 + quad * 8];
        const half8 v1 = *(const half8*)&Vt[l15 + 16][ch * 32 + quad * 8];
        __builtin_amdgcn_s_setprio(1);
        d0 = __builtin_amdgcn_mfma_f32_16x16x32_f16(pa, v0, d0, 0, 0, 0);
        d1 = __builtin_amdgcn_mfma_f32_16x16x32_f16(pa, v1, d1, 0, 0, 0);
        __builtin_amdgcn_s_setprio(0);
    }

    // ---- softmax denominator: lane holds partial for query l15 ----
    lsum += __shfl_xor(lsum, 16);
    lsum += __shfl_xor(lsum, 32);
    const float inv = 1.0f / lsum;     // full denom for query l15

    // ---- epilogue: D row = quad*4+reg (query), col = l15 (d) ----
    #pragma unroll
    for (int reg = 0; reg < 4; reg++) {
        const int q = quad * 4 + reg;
        const float invq = __shfl(inv, q);     // lane q (quad 0) holds query q
        const int gq = wave * 16 + q;
        const int oqr = gq >> 3, oqc = gq & 7;
        const int oy = wy * 8 + oqr, ox = wx * 8 + oqc;
        _Float16* op = out + (((size_t)(b * 128 + oy) * 128 + ox) * CC) + h * HD;
        op[l15]      = (_Float16)(d0[reg] * invq);
        op[16 + l15] = (_Float16)(d1[reg] * invq);
    }
}

// ---------------------------------------------------------------------------
extern "C" void kernel_launch(void* const* d_in, const int* in_sizes, int n_in,
                              void* d_out, int out_size, void* d_ws, size_t ws_size,
                              hipStream_t stream) {
    const float* x           = (const float*)d_in[0];
    const float* w_qkv       = (const float*)d_in[1];
    const float* w_dw        = (const float*)d_in[2];
    const float* ln_g        = (const float*)d_in[3];
    const float* ln_b        = (const float*)d_in[4];
    const float* q_bias      = (const float*)d_in[5];
    const float* v_bias      = (const float*)d_in[6];
    const float* logit_scale = (const float*)d_in[7];
    const float* cpb_w1      = (const float*)d_in[8];
    const float* cpb_b1      = (const float*)d_in[9];
    const float* cpb_w2      = (const float*)d_in[10];
    const float* w_proj      = (const float*)d_in[11];
    float* out = (float*)d_out;

    char* ws = (char*)d_ws;
    _Float16* attnh  = (_Float16*)(ws);                          // 16.78 MB
    _Float16* qkvh   = (_Float16*)(ws + 16777216);               // 50.33 MB
    _Float16* qkv0h  = (_Float16*)(ws + 67108864);               // 50.33 MB
    _Float16* wqkvT  = (_Float16*)(ws + 117440512);              // 0.39 MB
    _Float16* wprojT = (_Float16*)(ws + 117833728);              // 0.13 MB
    _Float16* wdwh   = (_Float16*)(ws + 117964800);              // 13.8 KB
    float*    btab   = (float*)   (ws + 117981184);              // 17 KB

    cpb_kernel<<<529, 64, 0, stream>>>(cpb_w1, cpb_b1, cpb_w2, btab);
    cvt_wdw<<<27, 256, 0, stream>>>(w_dw, wdwh);
    transpose_cvt<<<dim3(C3 / 32, CC / 32), 256, 0, stream>>>(w_qkv, wqkvT, CC, C3);
    transpose_cvt<<<dim3(CC / 32, CC / 32), 256, 0, stream>>>(w_proj, wprojT, CC, CC);

    // qkv0 = x @ w_qkv    (fused fp32->fp16 A convert)
    gemm_qkv<<<dim3(C3 / 128, NPIX / 128), 256, 0, stream>>>(
        x, wqkvT, qkv0h, NPIX, C3, CC);
    // depthwise 3x3 + LN + bias + Q/K pre-normalize  (8x2 2D tiles)
    dwconv_ln<<<NPIX / 16, 256, 0, stream>>>(qkv0h, wdwh, ln_g, ln_b, q_bias,
                                             v_bias, logit_scale, qkvh);
    // halo window attention (pre-normalized Q/K, Vt[32][264] layout)
    attn_mfma<<<NWIN * NHEADS, 256, 0, stream>>>(qkvh, btab, logit_scale, attnh);
    // out = attn_out @ w_proj   (fp32 out)
    gemm_f16<float><<<dim3(CC / 128, NPIX / 128), 256, 0, stream>>>(
        attnh, wprojT, out, NPIX, CC, CC);
}

// Round 11
// 235.969 us; speedup vs baseline: 1.0425x; 1.0425x over previous
//
#include <hip/hip_runtime.h>
#include <hip/hip_bf16.h>
#include <hip/hip_fp16.h>
#include <cstddef>
#include <cstdint>

// Problem constants
#define BB 2
#define HH 128
#define WW 128
#define CC 256
#define WSZ 8
#define KWIN 16
#define NHEADS 8
#define HD 32
#define C3 768
#define NPIX 32768            // B*H*W
#define NWIN 512              // B * 16 * 16

typedef short    bf16x8 __attribute__((ext_vector_type(8)));
typedef _Float16 half8  __attribute__((ext_vector_type(8)));
typedef float    f32x4  __attribute__((ext_vector_type(4)));

#define LOG2E 1.4426950408889634f

#if __has_builtin(__builtin_amdgcn_exp2f)
#define EXP2(x) __builtin_amdgcn_exp2f(x)
#else
#define EXP2(x) __expf((x) * 0.6931471805599453f)
#endif

__device__ inline void gload_lds16(const _Float16* g, _Float16* l) {
    __builtin_amdgcn_global_load_lds(
        (const __attribute__((address_space(1))) unsigned int*)g,
        (__attribute__((address_space(3))) unsigned int*)l, 16, 0, 0);
}

// ---------------------------------------------------------------------------
// CPB MLP: bias_tab[529][8] = sigmoid(relu(tab @ w1 + b1) @ w2) * 16
// ---------------------------------------------------------------------------
__global__ __launch_bounds__(64) void cpb_kernel(const float* __restrict__ w1,
                                                 const float* __restrict__ b1,
                                                 const float* __restrict__ w2,
                                                 float* __restrict__ btab) {
    const int e = blockIdx.x;          // 0..528
    const int i = e / 23, j = e % 23;
    const float inv_log8 = 1.0f / logf(8.0f);
    float c0 = (float)(i - 11) * (8.0f / 7.0f);
    float c1 = (float)(j - 11) * (8.0f / 7.0f);
    float f0 = copysignf(log1pf(fabsf(c0)) * inv_log8, c0);
    float f1 = copysignf(log1pf(fabsf(c1)) * inv_log8, c1);

    const int t = threadIdx.x;
    float acc[8] = {0.f,0.f,0.f,0.f,0.f,0.f,0.f,0.f};
    for (int kk = 0; kk < 8; kk++) {
        int k = kk * 64 + t;
        float hid = f0 * w1[k] + f1 * w1[512 + k] + b1[k];
        hid = fmaxf(hid, 0.f);
        #pragma unroll
        for (int h = 0; h < 8; h++) acc[h] += hid * w2[k * 8 + h];
    }
    #pragma unroll
    for (int h = 0; h < 8; h++) {
        #pragma unroll
        for (int off = 32; off >= 1; off >>= 1) acc[h] += __shfl_xor(acc[h], off);
    }
    if (t < 8) {
        float v = acc[t];
        btab[e * 8 + t] = 16.0f / (1.0f + expf(-v));
    }
}

// ---------------------------------------------------------------------------
// depthwise weights fp32 -> fp16 table (9*768 elems)
// ---------------------------------------------------------------------------
__global__ __launch_bounds__(256) void cvt_wdw(const float* __restrict__ src,
                                               _Float16* __restrict__ dst) {
    int i = blockIdx.x * 256 + threadIdx.x;
    if (i < 9 * C3) dst[i] = (_Float16)src[i];
}

// ---------------------------------------------------------------------------
// transpose + convert: src fp32 [R][Cn] -> dst fp16 [Cn][R].  32x32 LDS tile.
// ---------------------------------------------------------------------------
__global__ __launch_bounds__(256) void transpose_cvt(const float* __restrict__ src,
                                                     _Float16* __restrict__ dst,
                                                     int R, int Cn) {
    __shared__ float t[32][33];
    const int bx = blockIdx.x, by = blockIdx.y;
    const int tx = threadIdx.x & 31, ty = threadIdx.x >> 5;
    #pragma unroll
    for (int i = 0; i < 4; i++) {
        int r = by * 32 + ty + i * 8;
        t[ty + i * 8][tx] = src[(size_t)r * Cn + bx * 32 + tx];
    }
    __syncthreads();
    #pragma unroll
    for (int i = 0; i < 4; i++) {
        int dr = bx * 32 + ty + i * 8;          // orig col
        dst[(size_t)dr * R + by * 32 + tx] = (_Float16)t[tx][ty + i * 8];
    }
}

// ---------------------------------------------------------------------------
// fp16 MFMA NT-GEMM:  C[M][N] = A[M][K] * Bt[N][K]^T, fp32 accumulate.
// 128x128 tile, BK=64, 256 threads (4 waves, 2x2 of 64x64).
// v2: 1D grid + XCD-aware swizzle (T1): n = (bid&7)*(nwg/8) + (bid>>3),
// by = n/ncol, bx = n%ncol.  Under round-robin HW dispatch each XCD gets
// a contiguous row-band with col fastest -> the A row-panel is fetched
// once into that XCD's L2 and reused by all ncol column-blocks.
// LDS layout contract: physical k-slot p at row m holds logical group
// p ^ (m&7); fragment reads undo via phys = logical ^ (l15&7).
// ---------------------------------------------------------------------------
template <typename OT>
__global__ __launch_bounds__(256) void gemm_f16(const _Float16* __restrict__ A,
                                                const _Float16* __restrict__ Bt,
                                                OT* __restrict__ C,
                                                int M, int N, int K, int ncol) {
    __shared__ _Float16 Ash[128][64];
    __shared__ _Float16 Bsh[128][64];
    const int tid = threadIdx.x;
    const int wv = tid >> 6, ln = tid & 63;
    const int quad = ln >> 4, l15 = ln & 15;
    const int bid = blockIdx.x;
    const int n = (bid & 7) * (gridDim.x >> 3) + (bid >> 3);
    const int by = n / ncol, bx = n - by * ncol;
    const int rowb = by * 128;
    const int colb = bx * 128;
    const int wm = (wv >> 1) * 64, wn = (wv & 1) * 64;

    const int r8 = ln >> 3, g = ln & 7;
    const int kg = g ^ r8;                    // swizzled logical k-group

    f32x4 acc[4][4] = {};
    for (int k0 = 0; k0 < K; k0 += 64) {
        #pragma unroll
        for (int i = 0; i < 4; i++) {
            const int m = wv * 32 + i * 8 + r8;
            gload_lds16(A + (size_t)(rowb + m) * K + k0 + kg * 8,
                        &Ash[wv * 32 + i * 8][0]);
            gload_lds16(Bt + (size_t)(colb + m) * K + k0 + kg * 8,
                        &Bsh[wv * 32 + i * 8][0]);
        }
        __syncthreads();
        #pragma unroll
        for (int kk = 0; kk < 2; kk++) {
            const int phys = ((kk * 4 + quad) ^ (l15 & 7)) * 8;
            half8 a[4], b[4];
            #pragma unroll
            for (int i = 0; i < 4; i++)
                a[i] = *(const half8*)&Ash[wm + i * 16 + l15][phys];
            #pragma unroll
            for (int j = 0; j < 4; j++)
                b[j] = *(const half8*)&Bsh[wn + j * 16 + l15][phys];
            #pragma unroll
            for (int i = 0; i < 4; i++)
                #pragma unroll
                for (int j = 0; j < 4; j++)
                    acc[i][j] = __builtin_amdgcn_mfma_f32_16x16x32_f16(
                        a[i], b[j], acc[i][j], 0, 0, 0);
        }
        __syncthreads();
    }
    #pragma unroll
    for (int i = 0; i < 4; i++) {
        #pragma unroll
        for (int reg = 0; reg < 4; reg++) {
            const size_t row = rowb + wm + i * 16 + quad * 4 + reg;
            #pragma unroll
            for (int j = 0; j < 4; j++) {
                C[row * N + colb + wn + j * 16 + l15] = (OT)acc[i][j][reg];
            }
        }
    }
}

// ---------------------------------------------------------------------------
// qkv GEMM with fused fp32->fp16 A conversion (A = x fp32 [M][K]).
// v2: 1D grid + XCD-aware swizzle (see gemm_f16 header) — the fp32 A
// panel (131KB/row-block) was re-read 6x across 6 DIFFERENT XCDs under
// default dispatch (201MB HBM/L3 traffic); now all 6 column-blocks of a
// row-band run on one XCD and hit its L2.
// Manual A staging honors the layout contract (phys p holds logical
// p^(m&7)): lane loads logical group g, writes phys slot g^r8.
// ---------------------------------------------------------------------------
__global__ __launch_bounds__(256) void gemm_qkv(const float* __restrict__ A,
                                                const _Float16* __restrict__ Bt,
                                                _Float16* __restrict__ C,
                                                int M, int N, int K, int ncol) {
    __shared__ _Float16 Ash[128][64];
    __shared__ _Float16 Bsh[128][64];
    const int tid = threadIdx.x;
    const int wv = tid >> 6, ln = tid & 63;
    const int quad = ln >> 4, l15 = ln & 15;
    const int bid = blockIdx.x;
    const int n = (bid & 7) * (gridDim.x >> 3) + (bid >> 3);
    const int by = n / ncol, bx = n - by * ncol;
    const int rowb = by * 128;
    const int colb = bx * 128;
    const int wm = (wv >> 1) * 64, wn = (wv & 1) * 64;
    const int r8 = ln >> 3, g = ln & 7;
    const int kg = g ^ r8;

    f32x4 acc[4][4] = {};
    for (int k0 = 0; k0 < K; k0 += 64) {
        #pragma unroll
        for (int i = 0; i < 4; i++) {
            const int m = wv * 32 + i * 8 + r8;
            // load LOGICAL group g, write PHYSICAL slot g^r8
            const float* ap = A + (size_t)(rowb + m) * K + k0 + g * 8;
            const float4 a0 = *(const float4*)ap;
            const float4 a1 = *(const float4*)(ap + 4);
            half8 hv;
            hv[0] = (_Float16)a0.x; hv[1] = (_Float16)a0.y;
            hv[2] = (_Float16)a0.z; hv[3] = (_Float16)a0.w;
            hv[4] = (_Float16)a1.x; hv[5] = (_Float16)a1.y;
            hv[6] = (_Float16)a1.z; hv[7] = (_Float16)a1.w;
            *(half8*)&Ash[wv * 32 + i * 8 + r8][kg * 8] = hv;
            gload_lds16(Bt + (size_t)(colb + m) * K + k0 + kg * 8,
                        &Bsh[wv * 32 + i * 8][0]);
        }
        __syncthreads();
        #pragma unroll
        for (int kk = 0; kk < 2; kk++) {
            const int phys = ((kk * 4 + quad) ^ (l15 & 7)) * 8;
            half8 a[4], b[4];
            #pragma unroll
            for (int i = 0; i < 4; i++)
                a[i] = *(const half8*)&Ash[wm + i * 16 + l15][phys];
            #pragma unroll
            for (int j = 0; j < 4; j++)
                b[j] = *(const half8*)&Bsh[wn + j * 16 + l15][phys];
            #pragma unroll
            for (int i = 0; i < 4; i++)
                #pragma unroll
                for (int j = 0; j < 4; j++)
                    acc[i][j] = __builtin_amdgcn_mfma_f32_16x16x32_f16(
                        a[i], b[j], acc[i][j], 0, 0, 0);
        }
        __syncthreads();
    }
    #pragma unroll
    for (int i = 0; i < 4; i++) {
        #pragma unroll
        for (int reg = 0; reg < 4; reg++) {
            const size_t row = rowb + wm + i * 16 + quad * 4 + reg;
            #pragma unroll
            for (int j = 0; j < 4; j++) {
                C[row * N + colb + wn + j * 16 + l15] = (_Float16)acc[i][j][reg];
            }
        }
    }
}

// ---------------------------------------------------------------------------
// Depthwise 3x3 conv (SAME) + LayerNorm(768) + qkv bias + Q/K PRE-NORMALIZE.
// v10 (REVERTED from v11's 8x2 tile — R10: 40960B LDS left zero headroom,
// occupancy collapsed to 18%, dwconv 57.5us; 1x8 strip + 31KB is proven).
// Per-third staging: 30 cells x 32 units = 960 half8 units = 15KB/phase,
// double-buffered; shift-only index split (cell=u>>5, grp=u&31);
// phase-invariant descriptors; prefetch next third during conv.
// Q/K l2-normalization fused here (head = gidx>>2; the 4 lanes of one
// (pixel,head) are shfl_xor 8/16 apart).  Q scaled by lscale*log2e.
// Conv reads use XOR swizzle phys=(u&~7)|((u^c)&7).
// ---------------------------------------------------------------------------
__global__ __launch_bounds__(256) void dwconv_ln(const _Float16* __restrict__ in,
                                                 const _Float16* __restrict__ wdwh,
                                                 const float* __restrict__ g,
                                                 const float* __restrict__ bt,
                                                 const float* __restrict__ qb,
                                                 const float* __restrict__ vb,
                                                 const float* __restrict__ logit_scale,
                                                 _Float16* __restrict__ out) {
    __shared__ __align__(16) _Float16 S[2][960 * 8];   // 2 x 15 KB
    __shared__ float sred[4][8][2];

    const int t = threadIdx.x;
    const int pix0 = blockIdx.x * 8;
    const int b = pix0 >> 14, y = (pix0 >> 7) & 127, x0 = pix0 & 127;
    const int p = t & 7, gidx = t >> 3;     // gidx 0..31

    // per-thread head scale for the q third
    const float lsc_q = __expf(fminf(logit_scale[gidx >> 2], 4.60517019f)) * LOG2E;

    // ---- phase-invariant staging descriptors (4 units/thread) ----
    const _Float16* sp[4];
    int sphys[4];
    bool sok[4];
    #pragma unroll
    for (int k = 0; k < 4; k++) {
        const int u = t + k * 256;                 // 0..1023; valid < 960
        const int cell = u >> 5, grp = u & 31;     // shift-only split
        const int r = (cell >= 20) ? 2 : (cell >= 10 ? 1 : 0);
        const int c = cell - r * 10;
        const int yy = y + r - 1, xx = x0 + c - 1;
        const bool inb = ((unsigned)yy < 128u) && ((unsigned)xx < 128u);
        sok[k] = inb;
        sp[k] = in + (((size_t)(b * 128 + (inb ? yy : 0)) * 128 + (inb ? xx : 0)) * C3)
                   + grp * 8;
        sphys[k] = (u & ~7) | ((u ^ c) & 7);
    }

    // ---- stage phase s of third-channels into buffer buf ----
    auto STAGE = [&](int s, int buf) {
        #pragma unroll
        for (int k = 0; k < 4; k++) {
            if (k < 3 || t < 192) {                // u < 960
                half8 v = (half8)(_Float16)0;
                if (sok[k]) v = *(const half8*)(sp[k] + s * 256);
                *(half8*)&S[buf][sphys[k] * 8] = v;
            }
        }
    };

    STAGE(0, 0);
    float acc[3][8] = {};
    #pragma unroll
    for (int s = 0; s < 3; s++) {
        __syncthreads();
        if (s < 2) STAGE(s + 1, (s + 1) & 1);      // prefetch next third
        const _Float16* Sb = &S[s & 1][0];
        half8 w[9];
        #pragma unroll
        for (int tap = 0; tap < 9; tap++)
            w[tap] = *(const half8*)(wdwh + (tap * 96 + s * 32 + gidx) * 8);
        #pragma unroll
        for (int r = 0; r < 3; r++) {
            #pragma unroll
            for (int dx = 0; dx < 3; dx++) {
                const int cc = p + dx;
                const int u = (r * 10 + cc) * 32 + gidx;
                const int phys = (u & ~7) | ((u ^ cc) & 7);
                const half8 v = *(const half8*)&Sb[phys * 8];
                const half8 wt = w[r * 3 + dx];
                #pragma unroll
                for (int i = 0; i < 8; i++)
                    acc[s][i] += (float)v[i] * (float)wt[i];
            }
        }
    }

    // ---- LayerNorm reduction over 768 ch of pixel p ----
    float ls = 0.f, lss = 0.f;
    #pragma unroll
    for (int s = 0; s < 3; s++)
        #pragma unroll
        for (int i = 0; i < 8; i++) { ls += acc[s][i]; lss += acc[s][i] * acc[s][i]; }
    ls  += __shfl_xor(ls, 8);  lss += __shfl_xor(lss, 8);
    ls  += __shfl_xor(ls, 16); lss += __shfl_xor(lss, 16);
    ls  += __shfl_xor(ls, 32); lss += __shfl_xor(lss, 32);
    const int wv = t >> 6, lnid = t & 63;
    if (lnid < 8) { sred[wv][lnid][0] = ls; sred[wv][lnid][1] = lss; }
    __syncthreads();
    const float Ssum  = sred[0][p][0] + sred[1][p][0] + sred[2][p][0] + sred[3][p][0];
    const float SSsum = sred[0][p][1] + sred[1][p][1] + sred[2][p][1] + sred[3][p][1];
    const float mu  = Ssum * (1.0f / 768.0f);
    const float var = SSsum * (1.0f / 768.0f) - mu * mu;
    const float rs  = rsqrtf(var + 1e-5f);

    // ---- scale/shift + q/v bias + q/k head-normalize, store fp16 ----
    const size_t obase = (size_t)(pix0 + p) * C3;
    #pragma unroll
    for (int s = 0; s < 3; s++) {
        const int ch = gidx * 8 + s * 256;
        const float4 g0 = *(const float4*)(g + ch);
        const float4 g1 = *(const float4*)(g + ch + 4);
        const float4 b0 = *(const float4*)(bt + ch);
        const float4 b1 = *(const float4*)(bt + ch + 4);
        float gg[8] = {g0.x, g0.y, g0.z, g0.w, g1.x, g1.y, g1.z, g1.w};
        float bb[8] = {b0.x, b0.y, b0.z, b0.w, b1.x, b1.y, b1.z, b1.w};
        if (s == 0) {
            const float4 e0 = *(const float4*)(qb + ch);
            const float4 e1 = *(const float4*)(qb + ch + 4);
            bb[0] += e0.x; bb[1] += e0.y; bb[2] += e0.z; bb[3] += e0.w;
            bb[4] += e1.x; bb[5] += e1.y; bb[6] += e1.z; bb[7] += e1.w;
        } else if (s == 2) {
            const float4 e0 = *(const float4*)(vb + ch - 512);
            const float4 e1 = *(const float4*)(vb + ch - 512 + 4);
            bb[0] += e0.x; bb[1] += e0.y; bb[2] += e0.z; bb[3] += e0.w;
            bb[4] += e1.x; bb[5] += e1.y; bb[6] += e1.z; bb[7] += e1.w;
        }
        float of[8];
        #pragma unroll
        for (int i = 0; i < 8; i++)
            of[i] = (acc[s][i] - mu) * rs * gg[i] + bb[i];
        if (s < 2) {                       // q (s=0) / k (s=1): l2-normalize per head
            float s2 = 0.f;
            #pragma unroll
            for (int i = 0; i < 8; i++) s2 += of[i] * of[i];
            s2 += __shfl_xor(s2, 8);
            s2 += __shfl_xor(s2, 16);
            float scl = rsqrtf(fmaxf(s2, 1.55e-5f));
            if (s == 0) scl *= lsc_q;
            #pragma unroll
            for (int i = 0; i < 8; i++) of[i] *= scl;
        }
        half8 o;
        #pragma unroll
        for (int i = 0; i < 8; i++) o[i] = (_Float16)of[i];
        *(half8*)(out + obase + ch) = o;
    }
}

// ---------------------------------------------------------------------------
// MFMA halo window attention v7: swapped QK^T, lane-local P, bias-as-C-init,
// pre-normalized Q/K, and V in the proven Vt[32][264] layout.
//
// R9 post-mortem: the Vt2 key-major swizzle RAISED bank conflicts
// (3.67M -> 4.72M) — the per-element scatter writes cost more than the
// reads saved.  Vt[32][264]: b16 writes (2 lanes/bank = free), aligned
// b128 reads (row stride 528B = odd x 16B).
//
// P2SHIFT (+14 log2): static shift M=lscale+16 is the WORST-CASE logit
// bound; real max logits sit ~12 nats below, so unshifted p would be f16
// SUBNORMAL.  +14 lifts p into f16 normal range; p <= 2^14.2 < 65504,
// and the factor cancels exactly in d*inv.
// ---------------------------------------------------------------------------
#define P2SHIFT 14.0f

__global__ __launch_bounds__(256) void attn_mfma(const _Float16* __restrict__ qkv,
                                                 const float* __restrict__ bias_tab,
                                                 const float* __restrict__ logit_scale,
                                                 _Float16* __restrict__ out) {
    const int blk = blockIdx.x;
    const int h = blk & 7;
    const int wid = blk >> 3;
    const int b = wid >> 8;
    const int wy = (wid >> 4) & 15;
    const int wx = wid & 15;
    const int tid = threadIdx.x;
    const int wave = tid >> 6, lane = tid & 63;
    const int quad = lane >> 4, l15 = lane & 15;

    __shared__ __align__(16) _Float16 Bf[16 * 64 * 8];   // K in A-frag layout, 16 KB
    __shared__ __align__(16) _Float16 Vt[32][264];       // V^T f16, 16.5 KB
    __shared__ float btab[529];                          // (rb - M)*log2e + P2SHIFT

    const float lscale = __expf(fminf(logit_scale[h], 4.60517019f)); // ln(100)
    const float MshiftL2 = (lscale + 16.0f) * LOG2E - P2SHIFT;
    for (int e = tid; e < 529; e += 256)
        btab[e] = bias_tab[e * 8 + h] * LOG2E - MshiftL2;

    // ---- stage K (pure copy -> A-frag layout) and V^T, 1 key/thread ----
    {
        const int j = tid;                         // key 0..255
        const int kr = j >> 4, kcc = j & 15;
        const int gy = wy * 8 - 4 + kr, gx = wx * 8 - 4 + kcc;
        const bool inb = ((unsigned)gy < 128u) && ((unsigned)gx < 128u);
        const _Float16* p = qkv +
            (((size_t)(b * 128 + (inb ? gy : 0)) * 128 + (inb ? gx : 0)) * C3) +
            256 + h * HD;
        // K layout: tile nt, position pos
        const int nt  = ((j >> 5) << 1) | ((j >> 2) & 1);
        const int pos = (((j >> 3) & 3) << 2) | (j & 3);
        #pragma unroll
        for (int d8 = 0; d8 < 4; d8++) {
            half8 kk, vv;
            if (inb) { kk = *(const half8*)(p + d8 * 8); vv = *(const half8*)(p + 256 + d8 * 8); }
            else     { kk = (half8)(_Float16)0;          vv = (half8)(_Float16)0; }
            *(half8*)&Bf[((nt * 64) + d8 * 16 + pos) * 8] = kk;
            #pragma unroll
            for (int u = 0; u < 8; u++)
                Vt[d8 * 8 + u][j] = vv[u];
        }
    }

    // ---- per-wave Q B-fragment: direct load (pre-normalized & pre-scaled) ----
    const int qrow = wave * 16 + l15;
    const int qr = qrow >> 3, qc = qrow & 7;
    const int qy = wy * 8 + qr, qx = wx * 8 + qc;
    const half8 qfrag = *(const half8*)(qkv +
        (((size_t)(b * 128 + qy) * 128 + qx) * C3) + h * HD + quad * 8);
    __syncthreads();

    // ---- 8 chunks of 32 keys: bias-init -> S^T mfma -> exp2 -> PV ----
    // btab index for (ch,jj,reg): (qr - kr + 15)*23 + (qc - kc + 15)
    //   kr = 2ch + (quad>>1),  kc = (quad&1)*8 + 4jj + reg
    const int colbase = qc + 15 - ((quad & 1) << 3);
    const int rowq    = qr + 15 - (quad >> 1);
    float lsum = 0.f;
    f32x4 d0 = {0.f, 0.f, 0.f, 0.f};
    f32x4 d1 = {0.f, 0.f, 0.f, 0.f};
    #pragma unroll
    for (int ch = 0; ch < 8; ch++) {
        const half8 ka0 = *(const half8*)&Bf[((2 * ch)     * 64 + lane) * 8];
        const half8 ka1 = *(const half8*)&Bf[((2 * ch + 1) * 64 + lane) * 8];
        const float* bt = &btab[(rowq - 2 * ch) * 23 + colbase];
        f32x4 s0 = {bt[0],  bt[-1], bt[-2], bt[-3]};   // bias as C-init
        f32x4 s1 = {bt[-4], bt[-5], bt[-6], bt[-7]};
        __builtin_amdgcn_s_setprio(1);
        s0 = __builtin_amdgcn_mfma_f32_16x16x32_f16(ka0, qfrag, s0, 0, 0, 0);
        s1 = __builtin_amdgcn_mfma_f32_16x16x32_f16(ka1, qfrag, s1, 0, 0, 0);
        __builtin_amdgcn_s_setprio(0);
        half8 pa;
        #pragma unroll
        for (int r = 0; r < 4; r++) {
            const float p0 = EXP2(s0[r]);
            const float p1 = EXP2(s1[r]);
            lsum += p0 + p1;
            pa[r]     = (_Float16)p0;
            pa[4 + r] = (_Float16)p1;
        }
        const half8 v0 = *(const half8*)&Vt[l15][ch * 32 + quad * 8];
        const half8 v1 = *(const half8*)&Vt[l15 + 16][ch * 32 + quad * 8];
        __builtin_amdgcn_s_setprio(1);
        d0 = __builtin_amdgcn_mfma_f32_16x16x32_f16(pa, v0, d0, 0, 0, 0);
        d1 = __builtin_amdgcn_mfma_f32_16x16x32_f16(pa, v1, d1, 0, 0, 0);
        __builtin_amdgcn_s_setprio(0);
    }

    // ---- softmax denominator: lane holds partial for query l15 ----
    lsum += __shfl_xor(lsum, 16);
    lsum += __shfl_xor(lsum, 32);
    const float inv = 1.0f / lsum;     // full denom for query l15

    // ---- epilogue: D row = quad*4+reg (query), col = l15 (d) ----
    #pragma unroll
    for (int reg = 0; reg < 4; reg++) {
        const int q = quad * 4 + reg;
        const float invq = __shfl(inv, q);     // lane q (quad 0) holds query q
        const int gq = wave * 16 + q;
        const int oqr = gq >> 3, oqc = gq & 7;
        const int oy = wy * 8 + oqr, ox = wx * 8 + oqc;
        _Float16* op = out + (((size_t)(b * 128 + oy) * 128 + ox) * CC) + h * HD;
        op[l15]      = (_Float16)(d0[reg] * invq);
        op[16 + l15] = (_Float16)(d1[reg] * invq);
    }
}

// ---------------------------------------------------------------------------
extern "C" void kernel_launch(void* const* d_in, const int* in_sizes, int n_in,
                              void* d_out, int out_size, void* d_ws, size_t ws_size,
                              hipStream_t stream) {
    const float* x           = (const float*)d_in[0];
    const float* w_qkv       = (const float*)d_in[1];
    const float* w_dw        = (const float*)d_in[2];
    const float* ln_g        = (const float*)d_in[3];
    const float* ln_b        = (const float*)d_in[4];
    const float* q_bias      = (const float*)d_in[5];
    const float* v_bias      = (const float*)d_in[6];
    const float* logit_scale = (const float*)d_in[7];
    const float* cpb_w1      = (const float*)d_in[8];
    const float* cpb_b1      = (const float*)d_in[9];
    const float* cpb_w2      = (const float*)d_in[10];
    const float* w_proj      = (const float*)d_in[11];
    float* out = (float*)d_out;

    char* ws = (char*)d_ws;
    _Float16* attnh  = (_Float16*)(ws);                          // 16.78 MB
    _Float16* qkvh   = (_Float16*)(ws + 16777216);               // 50.33 MB
    _Float16* qkv0h  = (_Float16*)(ws + 67108864);               // 50.33 MB
    _Float16* wqkvT  = (_Float16*)(ws + 117440512);              // 0.39 MB
    _Float16* wprojT = (_Float16*)(ws + 117833728);              // 0.13 MB
    _Float16* wdwh   = (_Float16*)(ws + 117964800);              // 13.8 KB
    float*    btab   = (float*)   (ws + 117981184);              // 17 KB

    cpb_kernel<<<529, 64, 0, stream>>>(cpb_w1, cpb_b1, cpb_w2, btab);
    cvt_wdw<<<27, 256, 0, stream>>>(w_dw, wdwh);
    transpose_cvt<<<dim3(C3 / 32, CC / 32), 256, 0, stream>>>(w_qkv, wqkvT, CC, C3);
    transpose_cvt<<<dim3(CC / 32, CC / 32), 256, 0, stream>>>(w_proj, wprojT, CC, CC);

    // qkv0 = x @ w_qkv    (fused fp32->fp16 A convert, XCD-swizzled 1D grid)
    gemm_qkv<<<(C3 / 128) * (NPIX / 128), 256, 0, stream>>>(
        x, wqkvT, qkv0h, NPIX, C3, CC, C3 / 128);
    // depthwise 3x3 + LN + bias + Q/K pre-normalize  (v10: 1x8 strips)
    dwconv_ln<<<NPIX / 8, 256, 0, stream>>>(qkv0h, wdwh, ln_g, ln_b, q_bias,
                                            v_bias, logit_scale, qkvh);
    // halo window attention (pre-normalized Q/K, Vt[32][264] layout)
    attn_mfma<<<NWIN * NHEADS, 256, 0, stream>>>(qkvh, btab, logit_scale, attnh);
    // out = attn_out @ w_proj   (fp32 out, XCD-swizzled 1D grid)
    gemm_f16<float><<<(CC / 128) * (NPIX / 128), 256, 0, stream>>>(
        attnh, wprojT, out, NPIX, CC, CC, CC / 128);
}